// Round 3
// baseline (1520.648 us; speedup 1.0000x reference)
//
#include <hip/hip_runtime.h>
#include <hip/hip_bf16.h>

typedef __attribute__((ext_vector_type(8))) short short8;
typedef __attribute__((ext_vector_type(4))) float floatx4;
typedef __hip_bfloat16 bf16;

#define M1 1048576L  // 1024*1024

__device__ __forceinline__ float b2f(bf16 x) { return __bfloat162float(x); }

__device__ __forceinline__ void async16(const short* g, short* l) {
  __builtin_amdgcn_global_load_lds((const __attribute__((address_space(1))) void*)g,
                                   (__attribute__((address_space(3))) void*)l, 16, 0, 0);
}

// ---------------------------------------------------------------- GEMM ------
// C[M,N] = A[M,K] * B[K,N] (+bias[m]) ; A,B bf16; B passed TRANSPOSED:
// Bt [N][ldb] row-major. bias f32.
// flags: 1 = write C^T (layout [N][ldc], 4 contiguous m per lane)
//        2 = C is f32 (else bf16)
//        4 = accumulate into existing C (f32 C^T path)
struct GemmP {
  const short* A; const short* B; void* C; const float* bias;
  long sA1, sA2, sB1, sB2, sC1, sC2, sb1, sb2;
  int M, N, K, lda, ldb, ldc, Z2, flags;
};

__global__ __launch_bounds__(256) void gemm_kernel(GemmP p) {
  __shared__ __align__(16) short sA[128 * 32];
  __shared__ __align__(16) short sB[128 * 32];
  const int z = blockIdx.z, z1 = z / p.Z2, z2 = z % p.Z2;
  const short* A = p.A + z1 * p.sA1 + z2 * p.sA2;
  const short* B = p.B + z1 * p.sB1 + z2 * p.sB2;
  const long cOff = z1 * p.sC1 + z2 * p.sC2;
  const float* bias = p.bias ? (p.bias + z1 * p.sb1 + z2 * p.sb2) : (const float*)0;
  const int m0 = blockIdx.y * 128, n0 = blockIdx.x * 128;
  const int tid = threadIdx.x, wave = tid >> 6, lane = tid & 63;
  const int lane15 = lane & 15, quad = lane >> 4;
  const int mW = (wave & 1) * 64, nW = (wave >> 1) * 64;
  const int ldrow = lane >> 2;          // 0..15 within a 16-row chunk
  const int kcol = (lane & 3) * 8;      // 0,8,16,24

  floatx4 acc[4][4];
#pragma unroll
  for (int i = 0; i < 4; i++)
#pragma unroll
    for (int j = 0; j < 4; j++) { floatx4 zz = {0.f, 0.f, 0.f, 0.f}; acc[i][j] = zz; }

  for (int k0 = 0; k0 < p.K; k0 += 32) {
    __syncthreads();
#pragma unroll
    for (int it = 0; it < 2; it++) {
      const int ca = wave * 2 + it;     // chunk: rows ca*16 .. ca*16+15
      async16(A + (long)(m0 + ca * 16 + ldrow) * p.lda + k0 + kcol, sA + ca * 512);
      async16(B + (long)(n0 + ca * 16 + ldrow) * p.ldb + k0 + kcol, sB + ca * 512);
    }
    __syncthreads();
    short8 af[4], bfr[4];
#pragma unroll
    for (int mt = 0; mt < 4; mt++)
      af[mt] = *(const short8*)(sA + (mW + mt * 16 + lane15) * 32 + quad * 8);
#pragma unroll
    for (int nt = 0; nt < 4; nt++)
      bfr[nt] = *(const short8*)(sB + (nW + nt * 16 + lane15) * 32 + quad * 8);
#pragma unroll
    for (int mt = 0; mt < 4; mt++)
#pragma unroll
      for (int nt = 0; nt < 4; nt++)
        acc[mt][nt] = __builtin_amdgcn_mfma_f32_16x16x32_bf16(af[mt], bfr[nt], acc[mt][nt], 0, 0, 0);
  }

  const int fl = p.flags;
#pragma unroll
  for (int mt = 0; mt < 4; mt++)
#pragma unroll
    for (int nt = 0; nt < 4; nt++) {
      const int mg = m0 + mW + mt * 16 + quad * 4;
      const int ng = n0 + nW + nt * 16 + lane15;
      floatx4 v = acc[mt][nt];
      if (bias) {
        v.x += bias[mg + 0]; v.y += bias[mg + 1];
        v.z += bias[mg + 2]; v.w += bias[mg + 3];
      }
      if (fl & 1) {  // C^T: [N][ldc]
        const long o = cOff + (long)ng * p.ldc + mg;
        if (fl & 2) {
          float* cp = (float*)p.C + o;
          if (fl & 4) { v.x += cp[0]; v.y += cp[1]; v.z += cp[2]; v.w += cp[3]; }
          cp[0] = v.x; cp[1] = v.y; cp[2] = v.z; cp[3] = v.w;
        } else {
          bf16* cp = (bf16*)p.C + o;
          cp[0] = __float2bfloat16(v.x); cp[1] = __float2bfloat16(v.y);
          cp[2] = __float2bfloat16(v.z); cp[3] = __float2bfloat16(v.w);
        }
      } else {       // plain C: [M][ldc]
        const long o = cOff + (long)mg * p.ldc + ng;
        if (fl & 2) {
          float* cp = (float*)p.C + o;
          cp[0] = v.x; cp[p.ldc] = v.y; cp[2L * p.ldc] = v.z; cp[3L * p.ldc] = v.w;
        } else {
          bf16* cp = (bf16*)p.C + o;
          cp[0] = __float2bfloat16(v.x); cp[p.ldc] = __float2bfloat16(v.y);
          cp[2L * p.ldc] = __float2bfloat16(v.z); cp[3L * p.ldc] = __float2bfloat16(v.w);
        }
      }
    }
}

// -------------------------------------------------------- f32 -> bf16 -------
__global__ void cvt_k(const float* src, bf16* dst, long n) {
  long i = ((long)blockIdx.x * 256 + threadIdx.x) * 4;
  if (i + 3 < n) {
#pragma unroll
    for (int j = 0; j < 4; j++) dst[i + j] = __float2bfloat16(src[i + j]);
  }
}

// ------------------------------------------------------------ transpose -----
// in [B][C][D] f32 -> out [B][D][C] bf16
__global__ void trans_k(const float* in, bf16* out, int C, int D) {
  __shared__ float tile[32][33];
  const int d0 = blockIdx.x * 32, c0 = blockIdx.y * 32, b = blockIdx.z;
  const float* ib = in + (long)b * C * D;
  bf16* ob = out + (long)b * C * D;
  for (int i = threadIdx.y; i < 32; i += 8)
    tile[i][threadIdx.x] = ib[(long)(c0 + i) * D + d0 + threadIdx.x];
  __syncthreads();
  for (int i = threadIdx.y; i < 32; i += 8)
    ob[(long)(d0 + i) * C + c0 + threadIdx.x] = __float2bfloat16(tile[threadIdx.x][i]);
}

// ------------------------------------------------------ l2norm + metrics ----
// cross [3][4][1024 d][1024 c] f32 in-place; feat bf16 copy; metrics[3][4096]
__global__ __launch_bounds__(256) void norm_k(float* cross, bf16* feat, float* metrics) {
  const int blk = blockIdx.x;     // mod*4096 + pix
  const int mod = blk >> 12;
  float* base = cross + (long)blk * 1024;
  bf16* fb = feat + (long)blk * 1024;
  const int t = threadIdx.x;
  float v[4]; float ssq = 0.f;
#pragma unroll
  for (int j = 0; j < 4; j++) { v[j] = base[t + j * 256]; ssq += v[j] * v[j]; }
  __shared__ float r1[256], r2[256], r3[256];
  __shared__ float sinv;
  r1[t] = ssq; __syncthreads();
  for (int s = 128; s > 0; s >>= 1) { if (t < s) r1[t] += r1[t + s]; __syncthreads(); }
  if (t == 0) sinv = 1.0f / fmaxf(sqrtf(r1[0]), 1e-12f);
  __syncthreads();
  const float invn = sinv;
  float s1 = 0.f, s2 = 0.f, zc = 0.f;
#pragma unroll
  for (int j = 0; j < 4; j++) {
    float x = v[j] * invn; v[j] = x;
    s1 += x; s2 += x * x; if (x == 0.0f) zc += 1.0f;
  }
  r1[t] = s1; r2[t] = s2; r3[t] = zc; __syncthreads();
  for (int s = 128; s > 0; s >>= 1) {
    if (t < s) { r1[t] += r1[t + s]; r2[t] += r2[t + s]; r3[t] += r3[t + s]; }
    __syncthreads();
  }
  if (t == 0) {
    float m = (mod == 0) ? (r2[0] - r1[0] * r1[0] * (1.0f / 1024.f)) * (1.0f / 1023.f)
                         : r3[0] * (1.0f / 1024.f);
    metrics[blk] = m;
  }
#pragma unroll
  for (int j = 0; j < 4; j++) { base[t + j * 256] = v[j]; fb[t + j * 256] = __float2bfloat16(v[j]); }
}

// -------------------------------------------------------------- softmax -----
// S f32 [nrows][128], scale then softmax per row -> P bf16; 4 rows/block
__global__ void softmax_k(const float* S, bf16* P) {
  const int row = blockIdx.x * 4 + (threadIdx.x >> 6);
  const int lane = threadIdx.x & 63;
  const float sc = 0.08838834764831845f;   // 128^-0.5
  const float* sr = S + (long)row * 128;
  float a = sr[lane] * sc, b = sr[lane + 64] * sc;
  float m = fmaxf(a, b);
  for (int off = 32; off; off >>= 1) m = fmaxf(m, __shfl_xor(m, off));
  float e0 = expf(a - m), e1 = expf(b - m);
  float s = e0 + e1;
  for (int off = 32; off; off >>= 1) s += __shfl_xor(s, off);
  const float inv = 1.0f / s;
  bf16* pr = P + (long)row * 128;
  pr[lane] = __float2bfloat16(e0 * inv);
  pr[lane + 64] = __float2bfloat16(e1 * inv);
}

// ----------------------------------------------------------------- SE -------
__global__ void zero_k(float* p, int n) {
  int i = blockIdx.x * 256 + threadIdx.x;
  if (i < n) p[i] = 0.f;
}

__global__ void pool_k(const float* cross, float* pooled) {
  const int blk = blockIdx.x;          // mb*16 + seg, mb = mod*4+b
  const int seg = blk & 15, mb = blk >> 4;
  const float* base = cross + (long)mb * M1 + (long)seg * 64 * 1024;
  float* pout = pooled + (long)mb * 1024;
  for (int c = threadIdx.x; c < 1024; c += 256) {
    float s = 0.f;
    for (int d = 0; d < 64; d++) s += base[(long)d * 1024 + c];
    atomicAdd(&pout[c], s * (1.0f / 1024.0f));
  }
}

__global__ void se_k(const float* pooled, const float* w1, const float* b1,
                     const float* w2, const float* b2, float* gvec) {
  const int mb = blockIdx.x, mod = mb >> 2, t = threadIdx.x;
  __shared__ float ps[1024]; __shared__ float hs[64];
  const float* p = pooled + (long)mb * 1024;
  for (int c = t; c < 1024; c += 256) ps[c] = p[c];
  __syncthreads();
  if (t < 64) {
    const float* wr = w1 + (long)(mod * 64 + t) * 1024;
    float s = 0.f;
    for (int c = 0; c < 1024; c++) s += wr[c] * ps[c];
    s += b1[mod * 64 + t];
    hs[t] = fmaxf(s, 0.f);
  }
  __syncthreads();
  for (int o = t; o < 1024; o += 256) {
    const float* wr = w2 + (long)(mod * 1024 + o) * 64;
    float s = 0.f;
    for (int j = 0; j < 64; j++) s += wr[j] * hs[j];
    s += b2[mod * 1024 + o];
    gvec[(long)mb * 1024 + o] = 1.0f / (1.0f + expf(-s));
  }
}

// ------------------------------------------------------- gates + fused ------
__global__ __launch_bounds__(256) void gatefuse_k(const float* cross, const float* gvec,
    const float* metrics, const float* gw, const float* gb, bf16* fused) {
  const int pix = blockIdx.x;          // b*1024 + d
  const int b = pix >> 10, t = threadIdx.x;
  __shared__ float refbuf[3072];
  __shared__ float red[3][256];
  __shared__ float gsh[3];
  float p0 = 0.f, p1 = 0.f, p2 = 0.f;
  for (int mod = 0; mod < 3; mod++) {
    const float* cb = cross + ((long)mod * 4096 + pix) * 1024;
    const float* gv = gvec + (long)(mod * 4 + b) * 1024;
    for (int c = t; c < 1024; c += 256) {
      float val = cb[c] * gv[c];
      refbuf[mod * 1024 + c] = val;
      p0 += gw[0 * 3075 + mod * 1024 + c] * val;
      p1 += gw[1 * 3075 + mod * 1024 + c] * val;
      p2 += gw[2 * 3075 + mod * 1024 + c] * val;
    }
  }
  red[0][t] = p0; red[1][t] = p1; red[2][t] = p2; __syncthreads();
  for (int s = 128; s > 0; s >>= 1) {
    if (t < s) { red[0][t] += red[0][t + s]; red[1][t] += red[1][t + s]; red[2][t] += red[2][t + s]; }
    __syncthreads();
  }
  if (t == 0) {
    const float var = metrics[pix], spd = metrics[4096 + pix], spl = metrics[8192 + pix];
    for (int j = 0; j < 3; j++) {
      float s = red[j][0] + gw[j * 3075 + 3072] * var + gw[j * 3075 + 3073] * spd
              + gw[j * 3075 + 3074] * spl + gb[j];
      gsh[j] = 1.0f / (1.0f + expf(-s));
    }
  }
  __syncthreads();
  bf16* fb = fused + (long)pix * 3072;
  for (int i = t; i < 3072; i += 256) fb[i] = __float2bfloat16(refbuf[i] * gsh[i >> 10]);
}

// ---------------------------------------------------------------- host ------
extern "C" void kernel_launch(void* const* d_in, const int* in_sizes, int n_in,
                              void* d_out, int out_size, void* d_ws, size_t ws_size,
                              hipStream_t stream) {
  // ALL reference inputs/outputs are float32.
  const float* rgb = (const float*)d_in[0];
  const float* dep = (const float*)d_in[1];
  const float* lid = (const float*)d_in[2];
  const float* pw[3] = {(const float*)d_in[3], (const float*)d_in[5], (const float*)d_in[7]};
  const float* pb[3] = {(const float*)d_in[4], (const float*)d_in[6], (const float*)d_in[8]};
  const float* qw = (const float*)d_in[9];  const float* qb = (const float*)d_in[10];
  const float* kw = (const float*)d_in[11]; const float* kb = (const float*)d_in[12];
  const float* vw = (const float*)d_in[13]; const float* vb = (const float*)d_in[14];
  const float* ow = (const float*)d_in[15]; const float* obv = (const float*)d_in[16];
  const float* sew1 = (const float*)d_in[17]; const float* seb1 = (const float*)d_in[18];
  const float* sew2 = (const float*)d_in[19]; const float* seb2 = (const float*)d_in[20];
  const float* gw = (const float*)d_in[21];   const float* gb = (const float*)d_in[22];
  const float* fw = (const float*)d_in[23]; const float* fbias = (const float*)d_in[24];

  // ---- workspace: ~107 MB peak (lifetime-aliased; round-2 proven size) ----
  char* wp = (char*)d_ws;
  auto carve = [&](size_t bytes) -> char* {
    char* r = wp; wp += (bytes + 255) & ~(size_t)255; return r;
  };
  float* cross = (float*)carve(12L * M1 * 4);    // [3][4][1024 d][1024 c] f32, persists
  short* feat  = (short*)carve(12L * M1 * 2);    // [3][4][1024 d][1024 c] bf16; dead after attn -> fw_bf16
  char*  S     = carve(35L * 1024 * 1024);       // shared scratch region
  float* metrics = (float*)carve(3L * 4096 * 4);
  float* pooled  = (float*)carve(12L * 1024 * 4);
  float* gvec    = (float*)carve(12L * 1024 * 4);

  // S phase 1 (dead after projections):
  short* rgbT = (short*)S;                          // 4 MB  [4][1024 d][512 c] bf16
  short* depT = (short*)(S + 4L  * 1024 * 1024);    // 2 MB
  short* lidT = (short*)(S + 6L  * 1024 * 1024);    // 0.5 MB
  short* pwb[3] = {(short*)(S + 8L * 1024 * 1024),  // 1 MB
                   (short*)(S + 9L * 1024 * 1024),  // 0.5 MB
                   (short*)(S + 9728L * 1024)};     // 0.125 MB
  // S phase 2 (per attention block i):
  short* Qi  = (short*)S;                           // 8 MB [4][1024 c][1024 d]
  short* Ki  = (short*)(S + 8L  * 1024 * 1024);     // 8 MB
  short* Vi  = (short*)(S + 16L * 1024 * 1024);     // 8 MB [4][1024 d][1024 c]
  short* OAi = (short*)(S + 24L * 1024 * 1024);     // 8 MB [4][1024 d][1024 c]
  float* SC  = (float*)(S + 32L * 1024 * 1024);     // 2 MB [4][8][128][128]
  short* P   = (short*)(S + 34L * 1024 * 1024);     // 1 MB bf16
  short* wqb = (short*)(S + 24L * 1024 * 1024);     // 2 MB (OAi slot; dead until PV)
  short* wkb = (short*)(S + 26L * 1024 * 1024);     // 2 MB
  short* wvb = (short*)(S + 28L * 1024 * 1024);     // 2 MB
  short* wob = (short*)(S + 32L * 1024 * 1024);     // 2 MB (SC slot; after softmax)
  // S phase 3:
  short* fused = (short*)S;                         // 24 MB [4][1024 d][3072 c] bf16
  short* fwb   = feat;                              // 18 MB (feat slot; dead after attn)

  auto G = [&](dim3 grid, GemmP g) { gemm_kernel<<<grid, dim3(256), 0, stream>>>(g); };
  auto CVT = [&](const float* s, short* d, long n) {
    cvt_k<<<dim3((unsigned)(n / 1024)), dim3(256), 0, stream>>>(s, (bf16*)d, n);
  };

  // 1) transpose+convert raw inputs [B,C,D] f32 -> [B,D,C] bf16
  trans_k<<<dim3(32, 16, 4), dim3(32, 8), 0, stream>>>(rgb, (bf16*)rgbT, 512, 1024);
  trans_k<<<dim3(32, 8, 4),  dim3(32, 8), 0, stream>>>(dep, (bf16*)depT, 256, 1024);
  trans_k<<<dim3(32, 2, 4),  dim3(32, 8), 0, stream>>>(lid, (bf16*)lidT, 64, 1024);

  // 2) projections -> cross (f32, pixel-major, C^T write)
  {
    const int Ks[3] = {512, 256, 64};
    const short* Bts[3] = {rgbT, depT, lidT};
    for (int m = 0; m < 3; m++) {
      CVT(pw[m], pwb[m], 1024L * Ks[m]);
      GemmP g{}; g.A = pwb[m]; g.B = Bts[m]; g.C = cross + (long)m * 4 * M1; g.bias = pb[m];
      g.sB1 = (long)1024 * Ks[m]; g.sC1 = M1;
      g.M = 1024; g.N = 1024; g.K = Ks[m]; g.lda = Ks[m]; g.ldb = Ks[m]; g.ldc = 1024;
      g.Z2 = 1; g.flags = 1 | 2;
      G(dim3(8, 8, 4), g);
    }
  }

  // 3) l2norm (in-place) + bf16 feat copy + quality metrics
  norm_k<<<dim3(12288), dim3(256), 0, stream>>>(cross, (bf16*)feat, metrics);

  // 4) attention blocks one at a time (scratch reused)
  {
    const int qm[6] = {0, 0, 1, 1, 2, 2};  // query modality
    const int km[6] = {1, 2, 0, 2, 0, 1};  // kv modality
    for (int i = 0; i < 6; i++) {
      CVT(qw + (long)i * M1, wqb, M1);
      CVT(kw + (long)i * M1, wkb, M1);
      CVT(vw + (long)i * M1, wvb, M1);
      // Q conv -> Qi [b][c][d] (plain C)
      GemmP g{}; g.A = wqb; g.B = feat + (long)qm[i] * 4 * M1;
      g.C = Qi; g.bias = qb + i * 1024;
      g.sB2 = M1; g.sC2 = M1;
      g.M = 1024; g.N = 1024; g.K = 1024; g.lda = 1024; g.ldb = 1024; g.ldc = 1024;
      g.Z2 = 4; g.flags = 0;
      G(dim3(8, 8, 4), g);
      // K conv -> Ki [b][c][d] (plain C)
      GemmP h = g; h.A = wkb; h.B = feat + (long)km[i] * 4 * M1;
      h.C = Ki; h.bias = kb + i * 1024;
      G(dim3(8, 8, 4), h);
      // V conv -> Vi [b][d][c] (C^T)
      GemmP v = h; v.A = wvb; v.C = Vi; v.bias = vb + i * 1024; v.flags = 1;
      G(dim3(8, 8, 4), v);
      // scores: per (b,h): Qh[128,1024] x Kh[128,1024]^T -> SC[b][h][128][128] f32
      GemmP s{}; s.A = Qi; s.B = Ki; s.C = SC;
      s.sA1 = M1; s.sA2 = 131072; s.sB1 = M1; s.sB2 = 131072;
      s.sC1 = 131072; s.sC2 = 16384;
      s.M = 128; s.N = 128; s.K = 1024; s.lda = 1024; s.ldb = 1024; s.ldc = 128;
      s.Z2 = 8; s.flags = 2;
      G(dim3(1, 1, 32), s);
      // softmax (scale inside) -> P bf16; 4096 rows
      softmax_k<<<dim3(1024), dim3(256), 0, stream>>>(SC, (bf16*)P);
      // Wo conversion into SC slot (SC dead after softmax)
      CVT(ow + (long)i * M1, wob, M1);
      // PV: per (b,h): P[128,128] x Vh[128,1024] -> OAi (C^T pixel-major, col off h*128)
      GemmP pv{}; pv.A = P; pv.B = Vi; pv.C = OAi;
      pv.sA1 = 131072; pv.sA2 = 16384; pv.sB1 = M1; pv.sB2 = 128;
      pv.sC1 = M1; pv.sC2 = 128;
      pv.M = 128; pv.N = 1024; pv.K = 128; pv.lda = 128; pv.ldb = 1024; pv.ldc = 1024;
      pv.Z2 = 8; pv.flags = 1;
      G(dim3(8, 1, 32), pv);
      // O conv: cross[qm] += W_o[i] @ OAi + b_o[i]  (f32 C^T accumulate)
      GemmP o{}; o.A = wob; o.B = OAi;
      o.C = cross + (long)qm[i] * 4 * M1; o.bias = obv + i * 1024;
      o.sB1 = M1; o.sC1 = M1;   // z1 = batch (Z2=1)
      o.M = 1024; o.N = 1024; o.K = 1024; o.lda = 1024; o.ldb = 1024; o.ldc = 1024;
      o.Z2 = 1; o.flags = 1 | 2 | 4;
      G(dim3(8, 8, 4), o);
    }
  }

  // 5) SE: zero + pool (atomic partials) -> dense -> gvec
  zero_k<<<dim3(48), dim3(256), 0, stream>>>(pooled, 12 * 1024);
  pool_k<<<dim3(192), dim3(256), 0, stream>>>(cross, pooled);
  se_k<<<dim3(12), dim3(256), 0, stream>>>(pooled, sew1, seb1, sew2, seb2, gvec);

  // 6) per-pixel gates + fused (bf16, pixel-major [B][D][3072])
  gatefuse_k<<<dim3(4096), dim3(256), 0, stream>>>(cross, gvec, metrics, gw, gb, (bf16*)fused);

  // 7) fusion conv -> d_out [B][3072][1024] f32 (plain-C)
  {
    CVT(fw, fwb, 9L * M1);
    GemmP g{}; g.A = fwb; g.B = fused; g.C = d_out; g.bias = fbias;
    g.sB1 = (long)1024 * 3072; g.sC1 = (long)3072 * 1024;
    g.M = 3072; g.N = 1024; g.K = 3072; g.lda = 3072; g.ldb = 3072; g.ldc = 1024;
    g.Z2 = 1; g.flags = 2;
    G(dim3(8, 24, 4), g);
  }
  (void)in_sizes; (void)n_in; (void)out_size; (void)ws_size;
}